// Round 2
// baseline (782.874 us; speedup 1.0000x reference)
//
#include <hip/hip_runtime.h>

// VposeFiled_Vjmlp: RFF encode + 80-group weight-norm MLP chain (480->512->512->256->6)
// Pipeline: prep_w (weight-norm -> bf16), prep_x (RFF + transpose-gather -> bf16),
//           mlp (fused 4-layer grouped GEMM chain, MFMA bf16, intermediates in LDS).

typedef __attribute__((ext_vector_type(8))) short short8;
typedef __attribute__((ext_vector_type(4))) float f32x4;
typedef __attribute__((ext_vector_type(4))) unsigned short ushort4v;

#define VJ    80
#define FS    480
#define HD2   512
#define HD    256
#define BATCH 2048

static __device__ __forceinline__ unsigned short f2bf(float f) {
  unsigned int u = __builtin_bit_cast(unsigned int, f);
  u += 0x7FFFu + ((u >> 16) & 1u);          // round-to-nearest-even
  return (unsigned short)(u >> 16);
}
static __device__ __forceinline__ float bf2f(unsigned short h) {
  unsigned int u = ((unsigned int)h) << 16;
  return __builtin_bit_cast(float, u);
}

// ---------------------------------------------------------------------------
// Kernel 1: weight-norm -> bf16 weights.  One wave per output row.
// w[o,:] = g[o] * v[o,:] / ||v[o,:]||
// ---------------------------------------------------------------------------
__global__ void prep_w(const float* __restrict__ v, const float* __restrict__ gain,
                       unsigned short* __restrict__ wout, int rows, int din) {
  int row  = blockIdx.x * 4 + (threadIdx.x >> 6);
  int lane = threadIdx.x & 63;
  if (row >= rows) return;
  const float* vr = v + (size_t)row * din;
  float s = 0.f;
  for (int k = lane; k < din; k += 64) { float x = vr[k]; s += x * x; }
  #pragma unroll
  for (int off = 32; off > 0; off >>= 1) s += __shfl_down(s, off);
  s = __shfl(s, 0);
  float scale = gain[row] / sqrtf(s);
  unsigned short* wr = wout + (size_t)row * din;
  for (int k = lane; k < din; k += 64) wr[k] = f2bf(vr[k] * scale);
}

// ---------------------------------------------------------------------------
// Kernel 2: x = pf + [cos|sin](2pi * qp @ B_rff), then the transpose-reshape
// gather into Xg[g][b][i] bf16, i = cl*80 + n, c = g*6 + cl.
// One block per batch element; LDS transpose tile [480][84] (pad 84 vs 80).
// ---------------------------------------------------------------------------
__global__ void __launch_bounds__(512)
prep_x(const float* __restrict__ qp, const float* __restrict__ pf,
       const float* __restrict__ Brff, unsigned short* __restrict__ Xg) {
  __shared__ float sB[720];          // [3][240]
  __shared__ float sQ[240];          // [80][3]
  __shared__ unsigned short sX[480 * 84];  // [c][n], stride 84
  const int b = blockIdx.x;
  const int t = threadIdx.x;
  // FIX (R1): blockDim is 512, sB has 720 entries -> must stride the load.
  // Previous `if (t < 720)` left sB[512..719] (B_rff z-row, k>=32) uninitialized.
  for (int i = t; i < 720; i += 512) sB[i] = Brff[i];
  if (t < 240) sQ[t] = qp[(size_t)b * 240 + t];
  __syncthreads();
  const float* pfb = pf + (size_t)b * 38400;
  for (int idx = t; idx < 38400; idx += 512) {
    int n = idx / 480;
    int c = idx - n * 480;
    int k = (c < 240) ? c : c - 240;
    float d = sQ[n*3] * sB[k] + sQ[n*3+1] * sB[240+k] + sQ[n*3+2] * sB[480+k];
    float ang = 6.283185307179586f * d;
    float f = (c < 240) ? __cosf(ang) : __sinf(ang);
    sX[c * 84 + n] = f2bf(pfb[idx] + f);
  }
  __syncthreads();
  // write out: Xg[(g*2048 + b)*480 + i], 4 elems per thread (contiguous in n)
  for (int idx4 = t; idx4 < 9600; idx4 += 512) {
    int g  = idx4 / 120;
    int i4 = idx4 - g * 120;
    int i  = i4 * 4;
    int cl = i / 80;
    int n  = i - cl * 80;
    ushort4v val = *(const ushort4v*)&sX[(g*6 + cl) * 84 + n];
    *(ushort4v*)(Xg + ((size_t)g * BATCH + b) * 480 + i) = val;
  }
}

// ---------------------------------------------------------------------------
// Kernel 3: fused 4-layer grouped MLP. One workgroup = (group g, 64 rows).
// 8 waves; wave w owns output columns [w*N/8, (w+1)*N/8).
// MFMA 16x16x32 bf16: A (activations) from LDS, B (weights, row-major = B^T)
// from global with 1-deep register prefetch.  C layout: col=lane&15,
// row=(lane>>4)*4+reg (m89-verified).
// ---------------------------------------------------------------------------
template<int K, int N, int SI, int SO, bool ACT>
static __device__ __forceinline__ void run_layer(
    const unsigned short* __restrict__ sIn, unsigned short* __restrict__ sOut,
    const unsigned short* __restrict__ W, const float* __restrict__ bias,
    int wave, int lane) {
  constexpr int NF = N / 128;              // 16-col frags per wave (8 waves)
  const int nbase = wave * (N / 8);
  const int lr = lane & 15, lh = lane >> 4;

  f32x4 acc[4][NF];
  #pragma unroll
  for (int mi = 0; mi < 4; ++mi)
    #pragma unroll
    for (int ni = 0; ni < NF; ++ni) acc[mi][ni] = (f32x4){0.f, 0.f, 0.f, 0.f};

  const unsigned short* aB = sIn + lr * SI + lh * 8;
  const unsigned short* wB = W + (size_t)(nbase + lr) * K + lh * 8;

  short8 bcur[NF], bnxt[NF];
  #pragma unroll
  for (int ni = 0; ni < NF; ++ni)
    bcur[ni] = *(const short8*)(wB + ni * 16 * K);

  constexpr int KK = K / 32;
  #pragma unroll
  for (int kk = 0; kk < KK; ++kk) {
    const int k0 = kk * 32;
    if (kk + 1 < KK) {
      #pragma unroll
      for (int ni = 0; ni < NF; ++ni)
        bnxt[ni] = *(const short8*)(wB + ni * 16 * K + k0 + 32);
    }
    short8 a[4];
    #pragma unroll
    for (int mi = 0; mi < 4; ++mi)
      a[mi] = *(const short8*)(aB + mi * 16 * SI + k0);
    #pragma unroll
    for (int mi = 0; mi < 4; ++mi)
      #pragma unroll
      for (int ni = 0; ni < NF; ++ni)
        acc[mi][ni] = __builtin_amdgcn_mfma_f32_16x16x32_bf16(a[mi], bcur[ni], acc[mi][ni], 0, 0, 0);
    #pragma unroll
    for (int ni = 0; ni < NF; ++ni) bcur[ni] = bnxt[ni];
  }

  float bv[NF];
  #pragma unroll
  for (int ni = 0; ni < NF; ++ni) bv[ni] = bias[nbase + ni * 16 + lr];

  #pragma unroll
  for (int mi = 0; mi < 4; ++mi)
    #pragma unroll
    for (int ni = 0; ni < NF; ++ni)
      #pragma unroll
      for (int r = 0; r < 4; ++r) {
        float val = acc[mi][ni][r] + bv[ni];
        if (ACT) val = (val >= 0.f) ? val : 0.01f * val;
        sOut[(mi * 16 + lh * 4 + r) * SO + (nbase + ni * 16 + lr)] = f2bf(val);
      }
}

__global__ void __launch_bounds__(512, 2)
mlp_kernel(const unsigned short* __restrict__ Xg,
           const unsigned short* __restrict__ W0, const unsigned short* __restrict__ W1,
           const unsigned short* __restrict__ W2, const unsigned short* __restrict__ W3,
           const float* __restrict__ b0, const float* __restrict__ b1,
           const float* __restrict__ b2, const float* __restrict__ b3,
           float* __restrict__ out) {
  __shared__ unsigned short s0[64 * 520];
  __shared__ unsigned short s1[64 * 520];

  // XCD swizzle (bid%8 -> XCD heuristic): each XCD runs one group's 32 tiles
  // concurrently -> 1.28 MB of weights L2-resident.
  const int bid  = blockIdx.x;
  const int xcd  = bid & 7;
  const int local = bid >> 3;
  const int g    = xcd * 10 + (local >> 5);
  const int tile = local & 31;
  const int m0   = tile * 64;

  const int tid = threadIdx.x, wave = tid >> 6, lane = tid & 63;

  // stage X tile [64][480] -> s0 stride 488
  const unsigned short* Xs = Xg + ((size_t)g * BATCH + m0) * 480;
  for (int idx = tid; idx < 64 * 60; idx += 512) {
    int row = idx / 60, c = idx - row * 60;
    *(short8*)&s0[row * 488 + c * 8] = *(const short8*)(Xs + row * 480 + c * 8);
  }
  __syncthreads();

  run_layer<480, 512, 488, 520, true >(s0, s1, W0 + (size_t)g * 512 * 480, b0 + g * 512, wave, lane);
  __syncthreads();
  run_layer<512, 512, 520, 520, true >(s1, s0, W1 + (size_t)g * 512 * 512, b1 + g * 512, wave, lane);
  __syncthreads();
  run_layer<512, 256, 520, 520, true >(s0, s1, W2 + (size_t)g * 256 * 512, b2 + g * 256, wave, lane);
  __syncthreads();

  // layer 4: [64x256] @ [6x256]^T, tiny -> VALU
  {
    const int m = tid >> 3, o = tid & 7;
    if (o < 6) {
      const unsigned short* h = s1 + m * 520;
      const unsigned short* w = W3 + ((size_t)g * 6 + o) * 256;
      float sum = 0.f;
      #pragma unroll 8
      for (int k4 = 0; k4 < 64; ++k4) {
        ushort4v hv = *(const ushort4v*)(h + k4 * 4);
        ushort4v wv = *(const ushort4v*)(w + k4 * 4);
        sum += bf2f(hv[0]) * bf2f(wv[0]) + bf2f(hv[1]) * bf2f(wv[1])
             + bf2f(hv[2]) * bf2f(wv[2]) + bf2f(hv[3]) * bf2f(wv[3]);
      }
      out[((size_t)(m0 + m) * VJ + g) * 6 + o] = sum + b3[g * 6 + o];
    }
  }
}

// ---------------------------------------------------------------------------
extern "C" void kernel_launch(void* const* d_in, const int* in_sizes, int n_in,
                              void* d_out, int out_size, void* d_ws, size_t ws_size,
                              hipStream_t stream) {
  const float* qp   = (const float*)d_in[0];
  const float* pf   = (const float*)d_in[1];
  const float* Brff = (const float*)d_in[2];
  const float* v0 = (const float*)d_in[3];  const float* g0 = (const float*)d_in[4];  const float* b0 = (const float*)d_in[5];
  const float* v1 = (const float*)d_in[6];  const float* g1 = (const float*)d_in[7];  const float* b1 = (const float*)d_in[8];
  const float* v2 = (const float*)d_in[9];  const float* g2 = (const float*)d_in[10]; const float* b2 = (const float*)d_in[11];
  const float* v3 = (const float*)d_in[12]; const float* g3 = (const float*)d_in[13]; const float* b3 = (const float*)d_in[14];

  unsigned short* W0 = (unsigned short*)d_ws;                 // [80*512][480]
  unsigned short* W1 = W0 + (size_t)VJ * HD2 * FS;            // [80*512][512]
  unsigned short* W2 = W1 + (size_t)VJ * HD2 * HD2;           // [80*256][512]
  unsigned short* W3 = W2 + (size_t)VJ * HD  * HD2;           // [80*6][256]
  unsigned short* Xg = W3 + (size_t)VJ * 6 * HD;              // [80][2048][480]

  prep_w<<<dim3(10240), dim3(256), 0, stream>>>(v0, g0, W0, VJ * HD2, FS);
  prep_w<<<dim3(10240), dim3(256), 0, stream>>>(v1, g1, W1, VJ * HD2, HD2);
  prep_w<<<dim3(5120),  dim3(256), 0, stream>>>(v2, g2, W2, VJ * HD,  HD2);
  prep_w<<<dim3(120),   dim3(256), 0, stream>>>(v3, g3, W3, VJ * 6,   HD);
  prep_x<<<dim3(BATCH), dim3(512), 0, stream>>>(qp, pf, Brff, Xg);
  mlp_kernel<<<dim3(VJ * 32), dim3(512), 0, stream>>>(Xg, W0, W1, W2, W3,
                                                      b0, b1, b2, b3, (float*)d_out);
}

// Round 3
// 619.615 us; speedup vs baseline: 1.2635x; 1.2635x over previous
//
#include <hip/hip_runtime.h>

// VposeFiled_Vjmlp: RFF encode + 80-group weight-norm MLP chain (480->512->512->256->6)
// R3: (1) weights re-laid out in MFMA-fragment order (coalesced B loads, was 16-way
//     segmented), (2) depth-2 B prefetch, (3) prep_x conflict-free LDS + hw sin/cos.

typedef __attribute__((ext_vector_type(8))) short short8;
typedef __attribute__((ext_vector_type(4))) float f32x4;
typedef __attribute__((ext_vector_type(4))) unsigned short ushort4v;
typedef __attribute__((ext_vector_type(2))) unsigned int uint2v;

#define VJ    80
#define FS    480
#define HD2   512
#define HD    256
#define BATCH 2048

static __device__ __forceinline__ unsigned short f2bf(float f) {
  unsigned int u = __builtin_bit_cast(unsigned int, f);
  u += 0x7FFFu + ((u >> 16) & 1u);          // round-to-nearest-even
  return (unsigned short)(u >> 16);
}
static __device__ __forceinline__ float bf2f(unsigned short h) {
  unsigned int u = ((unsigned int)h) << 16;
  return __builtin_bit_cast(float, u);
}

// ---------------------------------------------------------------------------
// Kernel 1a: weight-norm -> bf16 in MFMA-fragment order.
// Per group, W[N][K] is stored as frags: frag(ni,kk) = 512 ushorts where
// lane l, elem j holds W[ni*16 + (l&15)][kk*32 + ((l>>4)<<3) + j].
// One block = 16 rows (one ni) of one group; 256 threads.
// ---------------------------------------------------------------------------
template<int K, int RPG>
__global__ void __launch_bounds__(256)
prep_wfrag(const float* __restrict__ v, const float* __restrict__ gain,
           unsigned short* __restrict__ dst) {
  constexpr int KK = K / 32;
  constexpr int KP = K + 4;                 // pad: avoids 16-way emit-read conflicts
  __shared__ float sV[16 * KP];
  __shared__ float sScale[16];
  const int blk = blockIdx.x, t = threadIdx.x;
  const int n0 = blk * 16;
  const int g  = n0 / RPG;
  const int ni = (n0 % RPG) >> 4;

  const f32x4* v4 = (const f32x4*)(v + (size_t)n0 * K);
  for (int idx = t; idx < 16 * K / 4; idx += 256) {
    int row = idx / (K / 4), rem = idx - row * (K / 4);
    *(f32x4*)&sV[row * KP + rem * 4] = v4[idx];
  }
  __syncthreads();

  const int wave = t >> 6, lane = t & 63;
  for (int r = wave; r < 16; r += 4) {
    float s = 0.f;
    for (int k = lane; k < K; k += 64) { float x = sV[r * KP + k]; s += x * x; }
    #pragma unroll
    for (int off = 32; off > 0; off >>= 1) s += __shfl_down(s, off);
    if (lane == 0) sScale[r] = gain[n0 + r] / sqrtf(s);
  }
  __syncthreads();

  unsigned short* db = dst + (size_t)g * RPG * K + (size_t)ni * KK * 512;
  for (int o = t; o < 2 * K; o += 256) {    // 2*K octets of 8 elems
    int f  = o >> 6, l = o & 63;
    int nl = l & 15, k0 = (f << 5) + (((l >> 4) & 3) << 3);
    float sc = sScale[nl];
    short8 pk;
    #pragma unroll
    for (int j = 0; j < 8; ++j) pk[j] = (short)f2bf(sV[nl * KP + k0 + j] * sc);
    *(short8*)&db[(size_t)f * 512 + l * 8] = pk;
  }
}

// ---------------------------------------------------------------------------
// Kernel 1b: row-major weight-norm (layer-3 tail weights only). Wave per row.
// ---------------------------------------------------------------------------
__global__ void prep_w(const float* __restrict__ v, const float* __restrict__ gain,
                       unsigned short* __restrict__ wout, int rows, int din) {
  int row  = blockIdx.x * 4 + (threadIdx.x >> 6);
  int lane = threadIdx.x & 63;
  if (row >= rows) return;
  const float* vr = v + (size_t)row * din;
  float s = 0.f;
  for (int k = lane; k < din; k += 64) { float x = vr[k]; s += x * x; }
  #pragma unroll
  for (int off = 32; off > 0; off >>= 1) s += __shfl_down(s, off);
  s = __shfl(s, 0);
  float scale = gain[row] / sqrtf(s);
  unsigned short* wr = wout + (size_t)row * din;
  for (int k = lane; k < din; k += 64) wr[k] = f2bf(vr[k] * scale);
}

// ---------------------------------------------------------------------------
// Kernel 2: x = pf + [cos|sin](2pi * qp @ B_rff); transpose-gather to
// Xg[g][b][i] bf16, i = cl*80 + n, c = g*6 + cl.
// Pairs batch-rows (n, n+1) per thread -> b32 LDS writes; stride 82 (odd word
// stride -> conflict-free); hw v_sin/v_cos take revolutions (no 2pi mul).
// ---------------------------------------------------------------------------
__global__ void __launch_bounds__(512)
prep_x(const float* __restrict__ qp, const float* __restrict__ pf,
       const float* __restrict__ Brff, unsigned short* __restrict__ Xg) {
  __shared__ float sB[720];                  // [3][240]
  __shared__ float sQ[240];                  // [80][3]
  __shared__ unsigned short sX[480 * 82];    // [c][n], stride 82
  const int b = blockIdx.x;
  const int t = threadIdx.x;
  for (int i = t; i < 720; i += 512) sB[i] = Brff[i];   // R1 fix: strided (720>512)
  if (t < 240) sQ[t] = qp[(size_t)b * 240 + t];
  __syncthreads();
  const float* pfb = pf + (size_t)b * 38400;
  for (int idx = t; idx < 19200; idx += 512) {
    int n2 = idx / 480;
    int c  = idx - n2 * 480;
    int n  = n2 * 2;
    int k  = (c < 240) ? c : c - 240;
    float bx = sB[k], by = sB[240 + k], bz = sB[480 + k];
    float d0 = sQ[n*3]   * bx + sQ[n*3+1] * by + sQ[n*3+2] * bz;
    float d1 = sQ[n*3+3] * bx + sQ[n*3+4] * by + sQ[n*3+5] * bz;
    // v_sin/v_cos input is in revolutions: sin(2*pi*d) == v_sin(d)
    float f0 = (c < 240) ? __builtin_amdgcn_cosf(d0) : __builtin_amdgcn_sinf(d0);
    float f1 = (c < 240) ? __builtin_amdgcn_cosf(d1) : __builtin_amdgcn_sinf(d1);
    unsigned int w = (unsigned int)f2bf(pfb[n * 480 + c] + f0)
                   | ((unsigned int)f2bf(pfb[(n + 1) * 480 + c] + f1) << 16);
    *(unsigned int*)&sX[c * 82 + n] = w;
  }
  __syncthreads();
  for (int idx4 = t; idx4 < 9600; idx4 += 512) {
    int g  = idx4 / 120;
    int i4 = idx4 - g * 120;
    int i  = i4 * 4;
    int cl = i / 80;
    int n  = i - cl * 80;
    const unsigned int* p = (const unsigned int*)&sX[(g * 6 + cl) * 82 + n]; // 4B-aligned
    uint2v val = { p[0], p[1] };
    *(uint2v*)(Xg + ((size_t)g * BATCH + b) * 480 + i) = val;
  }
}

// ---------------------------------------------------------------------------
// Kernel 3: fused 4-layer grouped MLP. One workgroup = (group g, 64 rows).
// 8 waves; wave w owns output cols [w*N/8, (w+1)*N/8). A from LDS
// (ds_read_b128), B from global in frag order (1 KB contiguous per load),
// depth-2 prefetch. C layout: col=lane&15, row=(lane>>4)*4+reg.
// ---------------------------------------------------------------------------
template<int K, int N, int SI, int SO, bool ACT>
static __device__ __forceinline__ void run_layer(
    const unsigned short* __restrict__ sIn, unsigned short* __restrict__ sOut,
    const unsigned short* __restrict__ Wf, const float* __restrict__ bias,
    int wave, int lane) {
  constexpr int NF = N / 128;
  constexpr int KK = K / 32;
  const int nbase = wave * (N / 8);
  const int lr = lane & 15, lh = lane >> 4;

  f32x4 acc[4][NF];
  #pragma unroll
  for (int mi = 0; mi < 4; ++mi)
    #pragma unroll
    for (int ni = 0; ni < NF; ++ni) acc[mi][ni] = (f32x4){0.f, 0.f, 0.f, 0.f};

  const unsigned short* aB = sIn + lr * SI + lh * 8;
  const unsigned short* wB = Wf + (size_t)(wave * NF) * KK * 512 + lane * 8;

  short8 b0[NF], b1[NF];
  #pragma unroll
  for (int ni = 0; ni < NF; ++ni) b0[ni] = *(const short8*)(wB + ((size_t)ni * KK    ) * 512);
  #pragma unroll
  for (int ni = 0; ni < NF; ++ni) b1[ni] = *(const short8*)(wB + ((size_t)ni * KK + 1) * 512);

  #pragma unroll
  for (int kk = 0; kk < KK; ++kk) {
    short8* bc = (kk & 1) ? b1 : b0;        // folds under full unroll (SSA)
    short8 a[4];
    #pragma unroll
    for (int mi = 0; mi < 4; ++mi)
      a[mi] = *(const short8*)(aB + mi * 16 * SI + kk * 32);
    #pragma unroll
    for (int mi = 0; mi < 4; ++mi)
      #pragma unroll
      for (int ni = 0; ni < NF; ++ni)
        acc[mi][ni] = __builtin_amdgcn_mfma_f32_16x16x32_bf16(a[mi], bc[ni], acc[mi][ni], 0, 0, 0);
    if (kk + 2 < KK) {
      #pragma unroll
      for (int ni = 0; ni < NF; ++ni)
        bc[ni] = *(const short8*)(wB + ((size_t)ni * KK + kk + 2) * 512);
    }
  }

  float bv[NF];
  #pragma unroll
  for (int ni = 0; ni < NF; ++ni) bv[ni] = bias[nbase + ni * 16 + lr];

  #pragma unroll
  for (int mi = 0; mi < 4; ++mi)
    #pragma unroll
    for (int ni = 0; ni < NF; ++ni)
      #pragma unroll
      for (int r = 0; r < 4; ++r) {
        float val = acc[mi][ni][r] + bv[ni];
        if (ACT) val = (val >= 0.f) ? val : 0.01f * val;
        sOut[(mi * 16 + lh * 4 + r) * SO + (nbase + ni * 16 + lr)] = f2bf(val);
      }
}

__global__ void __launch_bounds__(512, 2)
mlp_kernel(const unsigned short* __restrict__ Xg,
           const unsigned short* __restrict__ W0, const unsigned short* __restrict__ W1,
           const unsigned short* __restrict__ W2, const unsigned short* __restrict__ W3,
           const float* __restrict__ b0, const float* __restrict__ b1,
           const float* __restrict__ b2, const float* __restrict__ b3,
           float* __restrict__ out) {
  __shared__ unsigned short s0[64 * 520];
  __shared__ unsigned short s1[64 * 520];

  // XCD swizzle: consecutive bids round-robin XCDs; bids == x (mod 8) walk
  // tiles of group 10x first -> group weights (1.26 MB) stay L2-resident.
  const int bid   = blockIdx.x;
  const int xcd   = bid & 7;
  const int local = bid >> 3;
  const int g     = xcd * 10 + (local >> 5);
  const int tile  = local & 31;
  const int m0    = tile * 64;

  const int tid = threadIdx.x, wave = tid >> 6, lane = tid & 63;

  // stage X tile [64][480] -> s0 stride 488
  const unsigned short* Xs = Xg + ((size_t)g * BATCH + m0) * 480;
  for (int idx = tid; idx < 64 * 60; idx += 512) {
    int row = idx / 60, c = idx - row * 60;
    *(short8*)&s0[row * 488 + c * 8] = *(const short8*)(Xs + row * 480 + c * 8);
  }
  __syncthreads();

  run_layer<480, 512, 488, 520, true >(s0, s1, W0 + (size_t)g * 512 * 480, b0 + g * 512, wave, lane);
  __syncthreads();
  run_layer<512, 512, 520, 520, true >(s1, s0, W1 + (size_t)g * 512 * 512, b1 + g * 512, wave, lane);
  __syncthreads();
  run_layer<512, 256, 520, 520, true >(s0, s1, W2 + (size_t)g * 256 * 512, b2 + g * 256, wave, lane);
  __syncthreads();

  // layer 4: [64x256] @ [6x256]^T, tiny -> VALU
  {
    const int m = tid >> 3, o = tid & 7;
    if (o < 6) {
      const unsigned short* h = s1 + m * 520;
      const unsigned short* w = W3 + ((size_t)g * 6 + o) * 256;
      float sum = 0.f;
      #pragma unroll 8
      for (int k4 = 0; k4 < 64; ++k4) {
        ushort4v hv = *(const ushort4v*)(h + k4 * 4);
        ushort4v wv = *(const ushort4v*)(w + k4 * 4);
        sum += bf2f(hv[0]) * bf2f(wv[0]) + bf2f(hv[1]) * bf2f(wv[1])
             + bf2f(hv[2]) * bf2f(wv[2]) + bf2f(hv[3]) * bf2f(wv[3]);
      }
      out[((size_t)(m0 + m) * VJ + g) * 6 + o] = sum + b3[g * 6 + o];
    }
  }
}

// ---------------------------------------------------------------------------
extern "C" void kernel_launch(void* const* d_in, const int* in_sizes, int n_in,
                              void* d_out, int out_size, void* d_ws, size_t ws_size,
                              hipStream_t stream) {
  const float* qp   = (const float*)d_in[0];
  const float* pf   = (const float*)d_in[1];
  const float* Brff = (const float*)d_in[2];
  const float* v0 = (const float*)d_in[3];  const float* g0 = (const float*)d_in[4];  const float* b0 = (const float*)d_in[5];
  const float* v1 = (const float*)d_in[6];  const float* g1 = (const float*)d_in[7];  const float* b1 = (const float*)d_in[8];
  const float* v2 = (const float*)d_in[9];  const float* g2 = (const float*)d_in[10]; const float* b2 = (const float*)d_in[11];
  const float* v3 = (const float*)d_in[12]; const float* g3 = (const float*)d_in[13]; const float* b3 = (const float*)d_in[14];

  unsigned short* W0 = (unsigned short*)d_ws;                 // frag layout [80] groups
  unsigned short* W1 = W0 + (size_t)VJ * HD2 * FS;
  unsigned short* W2 = W1 + (size_t)VJ * HD2 * HD2;
  unsigned short* W3 = W2 + (size_t)VJ * HD  * HD2;           // row-major [480][256]
  unsigned short* Xg = W3 + (size_t)VJ * 6 * HD;              // [80][2048][480]

  prep_wfrag<480, 512><<<dim3(2560), dim3(256), 0, stream>>>(v0, g0, W0);
  prep_wfrag<512, 512><<<dim3(2560), dim3(256), 0, stream>>>(v1, g1, W1);
  prep_wfrag<512, 256><<<dim3(1280), dim3(256), 0, stream>>>(v2, g2, W2);
  prep_w<<<dim3(120), dim3(256), 0, stream>>>(v3, g3, W3, VJ * 6, HD);
  prep_x<<<dim3(BATCH), dim3(512), 0, stream>>>(qp, pf, Brff, Xg);
  mlp_kernel<<<dim3(VJ * 32), dim3(512), 0, stream>>>(Xg, W0, W1, W2, W3,
                                                      b0, b1, b2, b3, (float*)d_out);
}

// Round 4
// 590.673 us; speedup vs baseline: 1.3254x; 1.0490x over previous
//
#include <hip/hip_runtime.h>

// VposeFiled_Vjmlp: RFF encode + 80-group weight-norm MLP chain (480->512->512->256->6)
// R4: (1) remove B-prefetch pointer-select (was spilling b0/b1 to scratch, VGPR=88),
//     (2) single in-place LDS buffer -> 2 blocks/CU (occupancy 24->47%),
//     (3) all weight preps merged into one launch.

typedef __attribute__((ext_vector_type(8))) short short8;
typedef __attribute__((ext_vector_type(4))) float f32x4;
typedef __attribute__((ext_vector_type(4))) unsigned short ushort4v;
typedef __attribute__((ext_vector_type(2))) unsigned int uint2v;

#define VJ    80
#define FS    480
#define HD2   512
#define HD    256
#define BATCH 2048
#define SMLP  528   // LDS row stride (ushorts) for the mlp activation buffer

static __device__ __forceinline__ unsigned short f2bf(float f) {
  unsigned int u = __builtin_bit_cast(unsigned int, f);
  u += 0x7FFFu + ((u >> 16) & 1u);          // round-to-nearest-even
  return (unsigned short)(u >> 16);
}
static __device__ __forceinline__ float bf2f(unsigned short h) {
  unsigned int u = ((unsigned int)h) << 16;
  return __builtin_bit_cast(float, u);
}

// ---------------------------------------------------------------------------
// Weight prep (single launch). Blocks [0,2560): W0 frag; [2560,5120): W1 frag;
// [5120,6400): W2 frag; [6400,6520): W3 row-major.
// Frag layout per group: frag(ni,kk) = 512 ushorts; lane l elem j holds
// W[ni*16 + (l&15)][kk*32 + ((l>>4)<<3) + j].
// ---------------------------------------------------------------------------
template<int K, int RPG>
static __device__ __forceinline__ void wfrag_body(
    int blk, const float* __restrict__ v, const float* __restrict__ gain,
    unsigned short* __restrict__ dst, float* sV, float* sScale) {
  constexpr int KK = K / 32;
  constexpr int KP = K + 4;
  const int t  = threadIdx.x;
  const int n0 = blk * 16;
  const int g  = n0 / RPG;
  const int ni = (n0 % RPG) >> 4;

  const f32x4* v4 = (const f32x4*)(v + (size_t)n0 * K);
  for (int idx = t; idx < 16 * K / 4; idx += 256) {
    int row = idx / (K / 4), rem = idx - row * (K / 4);
    *(f32x4*)&sV[row * KP + rem * 4] = v4[idx];
  }
  __syncthreads();

  const int wave = t >> 6, lane = t & 63;
  for (int r = wave; r < 16; r += 4) {
    float s = 0.f;
    for (int k = lane; k < K; k += 64) { float x = sV[r * KP + k]; s += x * x; }
    #pragma unroll
    for (int off = 32; off > 0; off >>= 1) s += __shfl_down(s, off);
    if (lane == 0) sScale[r] = gain[n0 + r] / sqrtf(s);
  }
  __syncthreads();

  unsigned short* db = dst + (size_t)g * RPG * K + (size_t)ni * KK * 512;
  for (int o = t; o < 2 * K; o += 256) {
    int f  = o >> 6, l = o & 63;
    int nl = l & 15, k0 = (f << 5) + (((l >> 4) & 3) << 3);
    float sc = sScale[nl];
    short8 pk;
    #pragma unroll
    for (int j = 0; j < 8; ++j) pk[j] = (short)f2bf(sV[nl * KP + k0 + j] * sc);
    *(short8*)&db[(size_t)f * 512 + l * 8] = pk;
  }
}

static __device__ __forceinline__ void wrow_body(
    int blk, const float* __restrict__ v, const float* __restrict__ gain,
    unsigned short* __restrict__ wout, int rows, int din) {
  int row  = blk * 4 + (threadIdx.x >> 6);
  int lane = threadIdx.x & 63;
  if (row >= rows) return;
  const float* vr = v + (size_t)row * din;
  float s = 0.f;
  for (int k = lane; k < din; k += 64) { float x = vr[k]; s += x * x; }
  #pragma unroll
  for (int off = 32; off > 0; off >>= 1) s += __shfl_down(s, off);
  s = __shfl(s, 0);
  float scale = gain[row] / sqrtf(s);
  unsigned short* wr = wout + (size_t)row * din;
  for (int k = lane; k < din; k += 64) wr[k] = f2bf(vr[k] * scale);
}

__global__ void __launch_bounds__(256)
prep_weights(const float* __restrict__ v0, const float* __restrict__ g0,
             const float* __restrict__ v1, const float* __restrict__ g1,
             const float* __restrict__ v2, const float* __restrict__ g2,
             const float* __restrict__ v3, const float* __restrict__ g3,
             unsigned short* __restrict__ W0, unsigned short* __restrict__ W1,
             unsigned short* __restrict__ W2, unsigned short* __restrict__ W3) {
  __shared__ float sV[16 * 516];
  __shared__ float sScale[16];
  const int b = blockIdx.x;
  if      (b < 2560) wfrag_body<480, 512>(b,        v0, g0, W0, sV, sScale);
  else if (b < 5120) wfrag_body<512, 512>(b - 2560, v1, g1, W1, sV, sScale);
  else if (b < 6400) wfrag_body<512, 256>(b - 5120, v2, g2, W2, sV, sScale);
  else               wrow_body(b - 6400, v3, g3, W3, VJ * 6, HD);
}

// ---------------------------------------------------------------------------
// prep_x: x = pf + [cos|sin](2pi * qp @ B_rff); transpose-gather to
// Xg[g][b][i] bf16, i = cl*80 + n, c = g*6 + cl.  (unchanged from R3)
// ---------------------------------------------------------------------------
__global__ void __launch_bounds__(512)
prep_x(const float* __restrict__ qp, const float* __restrict__ pf,
       const float* __restrict__ Brff, unsigned short* __restrict__ Xg) {
  __shared__ float sB[720];                  // [3][240]
  __shared__ float sQ[240];                  // [80][3]
  __shared__ unsigned short sX[480 * 82];    // [c][n], stride 82
  const int b = blockIdx.x;
  const int t = threadIdx.x;
  for (int i = t; i < 720; i += 512) sB[i] = Brff[i];
  if (t < 240) sQ[t] = qp[(size_t)b * 240 + t];
  __syncthreads();
  const float* pfb = pf + (size_t)b * 38400;
  for (int idx = t; idx < 19200; idx += 512) {
    int n2 = idx / 480;
    int c  = idx - n2 * 480;
    int n  = n2 * 2;
    int k  = (c < 240) ? c : c - 240;
    float bx = sB[k], by = sB[240 + k], bz = sB[480 + k];
    float d0 = sQ[n*3]   * bx + sQ[n*3+1] * by + sQ[n*3+2] * bz;
    float d1 = sQ[n*3+3] * bx + sQ[n*3+4] * by + sQ[n*3+5] * bz;
    float f0 = (c < 240) ? __builtin_amdgcn_cosf(d0) : __builtin_amdgcn_sinf(d0);
    float f1 = (c < 240) ? __builtin_amdgcn_cosf(d1) : __builtin_amdgcn_sinf(d1);
    unsigned int w = (unsigned int)f2bf(pfb[n * 480 + c] + f0)
                   | ((unsigned int)f2bf(pfb[(n + 1) * 480 + c] + f1) << 16);
    *(unsigned int*)&sX[c * 82 + n] = w;
  }
  __syncthreads();
  for (int idx4 = t; idx4 < 9600; idx4 += 512) {
    int g  = idx4 / 120;
    int i4 = idx4 - g * 120;
    int i  = i4 * 4;
    int cl = i / 80;
    int n  = i - cl * 80;
    const unsigned int* p = (const unsigned int*)&sX[(g * 6 + cl) * 82 + n];
    uint2v val = { p[0], p[1] };
    *(uint2v*)(Xg + ((size_t)g * BATCH + b) * 480 + i) = val;
  }
}

// ---------------------------------------------------------------------------
// mlp: fused 4-layer grouped MLP, IN-PLACE single LDS buffer [64][SMLP].
// Per layer: all waves read everything -> sync -> write outputs -> sync.
// No pointer-selected prefetch: b[NF] constant-indexed, full unroll; the
// compiler software-pipelines the global B loads within the 128-VGPR cap.
// ---------------------------------------------------------------------------
template<int K, int N, bool ACT>
static __device__ __forceinline__ void run_layer_ip(
    unsigned short* __restrict__ s,
    const unsigned short* __restrict__ Wf, const float* __restrict__ bias,
    int wave, int lane) {
  constexpr int NF = N / 128;
  constexpr int KK = K / 32;
  const int nbase = wave * (N / 8);
  const int lr = lane & 15, lh = lane >> 4;

  float bv[NF];
  #pragma unroll
  for (int ni = 0; ni < NF; ++ni) bv[ni] = bias[nbase + ni * 16 + lr];

  f32x4 acc[4][NF];
  #pragma unroll
  for (int mi = 0; mi < 4; ++mi)
    #pragma unroll
    for (int ni = 0; ni < NF; ++ni) acc[mi][ni] = (f32x4){0.f, 0.f, 0.f, 0.f};

  const unsigned short* aB = s + lr * SMLP + lh * 8;
  const unsigned short* wB = Wf + (size_t)(wave * NF) * KK * 512 + lane * 8;

  #pragma unroll
  for (int kk = 0; kk < KK; ++kk) {
    short8 b[NF];
    #pragma unroll
    for (int ni = 0; ni < NF; ++ni)
      b[ni] = *(const short8*)(wB + ((size_t)ni * KK + kk) * 512);
    short8 a[4];
    #pragma unroll
    for (int mi = 0; mi < 4; ++mi)
      a[mi] = *(const short8*)(aB + mi * 16 * SMLP + kk * 32);
    #pragma unroll
    for (int mi = 0; mi < 4; ++mi)
      #pragma unroll
      for (int ni = 0; ni < NF; ++ni)
        acc[mi][ni] = __builtin_amdgcn_mfma_f32_16x16x32_bf16(a[mi], b[ni], acc[mi][ni], 0, 0, 0);
  }

  __syncthreads();   // every wave finished READING s
  #pragma unroll
  for (int mi = 0; mi < 4; ++mi)
    #pragma unroll
    for (int ni = 0; ni < NF; ++ni)
      #pragma unroll
      for (int r = 0; r < 4; ++r) {
        float val = acc[mi][ni][r] + bv[ni];
        if (ACT) val = (val >= 0.f) ? val : 0.01f * val;
        s[(mi * 16 + lh * 4 + r) * SMLP + (nbase + ni * 16 + lr)] = f2bf(val);
      }
  __syncthreads();   // writes visible before next layer reads
}

__global__ void __launch_bounds__(512, 4)
mlp_kernel(const unsigned short* __restrict__ Xg,
           const unsigned short* __restrict__ W0, const unsigned short* __restrict__ W1,
           const unsigned short* __restrict__ W2, const unsigned short* __restrict__ W3,
           const float* __restrict__ b0, const float* __restrict__ b1,
           const float* __restrict__ b2, const float* __restrict__ b3,
           float* __restrict__ out) {
  __shared__ unsigned short s[64 * SMLP];   // 67.6 KB -> 2 blocks/CU

  // XCD swizzle: bid%8 = XCD heuristic; each XCD walks its 10 groups' tiles.
  const int bid   = blockIdx.x;
  const int xcd   = bid & 7;
  const int local = bid >> 3;
  const int g     = xcd * 10 + (local >> 5);
  const int tile  = local & 31;
  const int m0    = tile * 64;

  const int tid = threadIdx.x, wave = tid >> 6, lane = tid & 63;

  // stage X tile [64][480]
  const unsigned short* Xs = Xg + ((size_t)g * BATCH + m0) * 480;
  for (int idx = tid; idx < 64 * 60; idx += 512) {
    int row = idx / 60, c = idx - row * 60;
    *(short8*)&s[row * SMLP + c * 8] = *(const short8*)(Xs + row * 480 + c * 8);
  }
  __syncthreads();

  run_layer_ip<480, 512, true>(s, W0 + (size_t)g * 512 * 480, b0 + g * 512, wave, lane);
  run_layer_ip<512, 512, true>(s, W1 + (size_t)g * 512 * 512, b1 + g * 512, wave, lane);
  run_layer_ip<512, 256, true>(s, W2 + (size_t)g * 256 * 512, b2 + g * 256, wave, lane);

  // layer 4: [64x256] @ [6x256]^T, tiny -> VALU
  {
    const int m = tid >> 3, o = tid & 7;
    if (o < 6) {
      const unsigned short* h = s + m * SMLP;
      const unsigned short* w = W3 + ((size_t)g * 6 + o) * 256;
      float sum = 0.f;
      #pragma unroll 8
      for (int k4 = 0; k4 < 64; ++k4) {
        ushort4v hv = *(const ushort4v*)(h + k4 * 4);
        ushort4v wv = *(const ushort4v*)(w + k4 * 4);
        sum += bf2f(hv[0]) * bf2f(wv[0]) + bf2f(hv[1]) * bf2f(wv[1])
             + bf2f(hv[2]) * bf2f(wv[2]) + bf2f(hv[3]) * bf2f(wv[3]);
      }
      out[((size_t)(m0 + m) * VJ + g) * 6 + o] = sum + b3[g * 6 + o];
    }
  }
}

// ---------------------------------------------------------------------------
extern "C" void kernel_launch(void* const* d_in, const int* in_sizes, int n_in,
                              void* d_out, int out_size, void* d_ws, size_t ws_size,
                              hipStream_t stream) {
  const float* qp   = (const float*)d_in[0];
  const float* pf   = (const float*)d_in[1];
  const float* Brff = (const float*)d_in[2];
  const float* v0 = (const float*)d_in[3];  const float* g0 = (const float*)d_in[4];  const float* b0 = (const float*)d_in[5];
  const float* v1 = (const float*)d_in[6];  const float* g1 = (const float*)d_in[7];  const float* b1 = (const float*)d_in[8];
  const float* v2 = (const float*)d_in[9];  const float* g2 = (const float*)d_in[10]; const float* b2 = (const float*)d_in[11];
  const float* v3 = (const float*)d_in[12]; const float* g3 = (const float*)d_in[13]; const float* b3 = (const float*)d_in[14];

  unsigned short* W0 = (unsigned short*)d_ws;                 // frag layout
  unsigned short* W1 = W0 + (size_t)VJ * HD2 * FS;
  unsigned short* W2 = W1 + (size_t)VJ * HD2 * HD2;
  unsigned short* W3 = W2 + (size_t)VJ * HD  * HD2;           // row-major [480][256]
  unsigned short* Xg = W3 + (size_t)VJ * 6 * HD;              // [80][2048][480]

  prep_weights<<<dim3(6520), dim3(256), 0, stream>>>(v0, g0, v1, g1, v2, g2, v3, g3,
                                                     W0, W1, W2, W3);
  prep_x<<<dim3(BATCH), dim3(512), 0, stream>>>(qp, pf, Brff, Xg);
  mlp_kernel<<<dim3(VJ * 32), dim3(512), 0, stream>>>(Xg, W0, W1, W2, W3,
                                                      b0, b1, b2, b3, (float*)d_out);
}